// Round 1
// baseline (328.560 us; speedup 1.0000x reference)
//
#include <hip/hip_runtime.h>
#include <hip/hip_bf16.h>

#define L 4096
#define CCH 256
#define NB 4
#define KP 40   // padded LDS row length (32 k + 8 pad) in bf16 elems; 80 B rows
#define GOF 72  // guarded-image front offset (alignment-friendly, >= 65)
#define LOG2E 1.4426950408889634f

typedef __attribute__((ext_vector_type(8))) short short8;
typedef __attribute__((ext_vector_type(4))) float f32x4;
typedef unsigned short ushort_t;

__device__ __forceinline__ unsigned short f2bf(float f) {
    unsigned u = __builtin_bit_cast(unsigned, f);
    u += 0x7FFF + ((u >> 16) & 1);
    return (unsigned short)(u >> 16);
}
// packed RNE f32x2 -> bf16x2; kept in GEMM epilogues / staging
__device__ __forceinline__ unsigned pk_bf16(float a, float b) {
    __hip_bfloat162 h = __float22bfloat162_rn(make_float2(a, b));
    unsigned u;
    __builtin_memcpy(&u, &h, 4);
    return u;
}
__device__ __forceinline__ float bflo(unsigned w) {
    return __builtin_bit_cast(float, w << 16);
}
__device__ __forceinline__ float bfhi(unsigned w) {
    return __builtin_bit_cast(float, w & 0xFFFF0000u);
}
__device__ __forceinline__ float bfu(ushort_t h) {
    return __builtin_bit_cast(float, (unsigned)h << 16);
}

// ---------------------------------------------------------------------------
// One-time weight conversion: w1|w2|wf (each 256x256 f32) -> bf16
// ---------------------------------------------------------------------------
__global__ __launch_bounds__(256) void wcvt_k(
    const float* __restrict__ w1, const float* __restrict__ w2,
    const float* __restrict__ wf,
    ushort_t* __restrict__ wb1, ushort_t* __restrict__ wb2,
    ushort_t* __restrict__ wbf)
{
    const int mb = blockIdx.x >> 6;          // 0..2: which matrix
    const int i  = (blockIdx.x & 63) * 256 + threadIdx.x;   // float4 index
    const float* src = (mb == 0) ? w1 : (mb == 1) ? w2 : wf;
    ushort_t*    dst = (mb == 0) ? wb1 : (mb == 1) ? wb2 : wbf;
    float4 v = ((const float4*)src)[i];
    uint2 p;
    p.x = pk_bf16(v.x, v.y);
    p.y = pk_bf16(v.z, v.w);
    ((uint2*)dst)[i] = p;
}

// ---------------------------------------------------------------------------
// Dual conv1x1 via bf16 MFMA (unchanged R13)
// ---------------------------------------------------------------------------
__global__ __launch_bounds__(256, 2) void dual_gemm_k(
    const float* __restrict__ x,
    const ushort_t* __restrict__ wb1, const float* __restrict__ b1,
    const ushort_t* __restrict__ wb2, const float* __restrict__ b2,
    ushort_t* __restrict__ y1, ushort_t* __restrict__ y2)
{
    __shared__ short sA1[128 * KP];
    __shared__ short sA2[128 * KP];
    __shared__ short sB [64 * KP];

    const int tid = threadIdx.x;
    const int l0 = blockIdx.x * 64;
    const int o0 = blockIdx.y * 128;
    const int b  = blockIdx.z;

    const int wv = tid >> 6;
    const int lane = tid & 63;
    const int m = lane & 15;
    const int quad = lane >> 4;

    const float* xb = x + (size_t)b * CCH * L;

    const int sl = tid & 63, soct = tid >> 6;
    const int sr = tid & 127, sh = tid >> 7;

    f32x4 acc1[2][4], acc2[2][4];
    #pragma unroll
    for (int io = 0; io < 2; ++io)
        #pragma unroll
        for (int jl = 0; jl < 4; ++jl) {
            acc1[io][jl] = (f32x4){0.f,0.f,0.f,0.f};
            acc2[io][jl] = (f32x4){0.f,0.f,0.f,0.f};
        }

    for (int s = 0; s < 8; ++s) {
        const int k0 = s * 32;
        __syncthreads();
        {
            const float* xs = xb + (size_t)(k0 + soct * 8) * L + l0 + sl;
            float f[8];
            #pragma unroll
            for (int j = 0; j < 8; ++j) f[j] = xs[(size_t)j * L];
            uint4 v;
            v.x = pk_bf16(f[0], f[1]);
            v.y = pk_bf16(f[2], f[3]);
            v.z = pk_bf16(f[4], f[5]);
            v.w = pk_bf16(f[6], f[7]);
            *(uint4*)&sB[sl * KP + soct * 8] = v;
        }
        {
            const uint4* wp = (const uint4*)&wb1[(size_t)(o0 + sr) * CCH + k0 + sh * 16];
            uint4 p0 = wp[0], p1 = wp[1];
            *(uint4*)&sA1[sr * KP + sh * 16]     = p0;
            *(uint4*)&sA1[sr * KP + sh * 16 + 8] = p1;
            const uint4* wq = (const uint4*)&wb2[(size_t)(o0 + sr) * CCH + k0 + sh * 16];
            uint4 q0 = wq[0], q1 = wq[1];
            *(uint4*)&sA2[sr * KP + sh * 16]     = q0;
            *(uint4*)&sA2[sr * KP + sh * 16 + 8] = q1;
        }
        __syncthreads();
        short8 a1[2], a2[2], bf[4];
        #pragma unroll
        for (int io = 0; io < 2; ++io) {
            a1[io] = *(const short8*)&sA1[(wv * 32 + io * 16 + m) * KP + quad * 8];
            a2[io] = *(const short8*)&sA2[(wv * 32 + io * 16 + m) * KP + quad * 8];
        }
        #pragma unroll
        for (int jl = 0; jl < 4; ++jl)
            bf[jl] = *(const short8*)&sB[(jl * 16 + m) * KP + quad * 8];
        #pragma unroll
        for (int io = 0; io < 2; ++io)
            #pragma unroll
            for (int jl = 0; jl < 4; ++jl) {
                acc1[io][jl] = __builtin_amdgcn_mfma_f32_16x16x32_bf16(a1[io], bf[jl], acc1[io][jl], 0, 0, 0);
                acc2[io][jl] = __builtin_amdgcn_mfma_f32_16x16x32_bf16(a2[io], bf[jl], acc2[io][jl], 0, 0, 0);
            }
    }

    #pragma unroll
    for (int io = 0; io < 2; ++io)
        #pragma unroll
        for (int reg = 0; reg < 4; ++reg) {
            const int o = o0 + wv * 32 + io * 16 + quad * 4 + reg;
            const float bb1 = b1[o], bb2 = b2[o];
            const size_t ro = ((size_t)b * CCH + o) * L + l0 + m;
            unsigned u1a = pk_bf16(acc1[io][0][reg] + bb1, acc1[io][1][reg] + bb1);
            unsigned u1b = pk_bf16(acc1[io][2][reg] + bb1, acc1[io][3][reg] + bb1);
            unsigned u2a = pk_bf16(acc2[io][0][reg] + bb2, acc2[io][1][reg] + bb2);
            unsigned u2b = pk_bf16(acc2[io][2][reg] + bb2, acc2[io][3][reg] + bb2);
            y1[ro]      = (ushort_t)u1a;
            y1[ro + 16] = (ushort_t)(u1a >> 16);
            y1[ro + 32] = (ushort_t)u1b;
            y1[ro + 48] = (ushort_t)(u1b >> 16);
            y2[ro]      = (ushort_t)u2a;
            y2[ro + 16] = (ushort_t)(u2a >> 16);
            y2[ro + 32] = (ushort_t)u2b;
            y2[ro + 48] = (ushort_t)(u2b >> 16);
        }
}

// ---------------------------------------------------------------------------
// Single conv1x1 via bf16 MFMA (unchanged R13)
// ---------------------------------------------------------------------------
__global__ __launch_bounds__(256, 2) void single_gemm_k(
    const ushort_t* __restrict__ x,
    const ushort_t* __restrict__ wb, const float* __restrict__ bb,
    ushort_t* __restrict__ y)
{
    __shared__ short sA[128 * KP];
    __shared__ short sB[64 * KP];

    const int tid = threadIdx.x;
    const int l0 = blockIdx.x * 64;
    const int o0 = blockIdx.y * 128;
    const int b  = blockIdx.z;

    const int wv = tid >> 6;
    const int lane = tid & 63;
    const int m = lane & 15;
    const int quad = lane >> 4;

    const ushort_t* xb = x + (size_t)b * CCH * L;

    const int sl = tid & 63, soct = tid >> 6;
    const int sr = tid & 127, sh = tid >> 7;

    f32x4 acc[2][4];
    #pragma unroll
    for (int io = 0; io < 2; ++io)
        #pragma unroll
        for (int jl = 0; jl < 4; ++jl)
            acc[io][jl] = (f32x4){0.f,0.f,0.f,0.f};

    for (int s = 0; s < 8; ++s) {
        const int k0 = s * 32;
        __syncthreads();
        {
            const ushort_t* xs = xb + (size_t)(k0 + soct * 8) * L + l0 + sl;
            short8 v;
            #pragma unroll
            for (int j = 0; j < 8; ++j) v[j] = (short)xs[(size_t)j * L];
            *(short8*)&sB[sl * KP + soct * 8] = v;
        }
        {
            const uint4* wp = (const uint4*)&wb[(size_t)(o0 + sr) * CCH + k0 + sh * 16];
            uint4 p0 = wp[0], p1 = wp[1];
            *(uint4*)&sA[sr * KP + sh * 16]     = p0;
            *(uint4*)&sA[sr * KP + sh * 16 + 8] = p1;
        }
        __syncthreads();
        short8 a[2], bf[4];
        #pragma unroll
        for (int io = 0; io < 2; ++io)
            a[io] = *(const short8*)&sA[(wv * 32 + io * 16 + m) * KP + quad * 8];
        #pragma unroll
        for (int jl = 0; jl < 4; ++jl)
            bf[jl] = *(const short8*)&sB[(jl * 16 + m) * KP + quad * 8];
        #pragma unroll
        for (int io = 0; io < 2; ++io)
            #pragma unroll
            for (int jl = 0; jl < 4; ++jl)
                acc[io][jl] = __builtin_amdgcn_mfma_f32_16x16x32_bf16(a[io], bf[jl], acc[io][jl], 0, 0, 0);
    }

    #pragma unroll
    for (int io = 0; io < 2; ++io)
        #pragma unroll
        for (int reg = 0; reg < 4; ++reg) {
            const int o = o0 + wv * 32 + io * 16 + quad * 4 + reg;
            const float b0 = bb[o];
            const size_t ro = ((size_t)b * CCH + o) * L + l0 + m;
            unsigned ua = pk_bf16(acc[io][0][reg] + b0, acc[io][1][reg] + b0);
            unsigned ub = pk_bf16(acc[io][2][reg] + b0, acc[io][3][reg] + b0);
            y[ro]      = (ushort_t)ua;
            y[ro + 16] = (ushort_t)(ua >> 16);
            y[ro + 32] = (ushort_t)ub;
            y[ro + 48] = (ushort_t)(ub >> 16);
        }
}

// ---------------------------------------------------------------------------
// BatchNorm stats over bf16 tensor -> finalized scale/shift.
// kscale: extra factor folded into scale/shift (log2e for the K channel).
// ---------------------------------------------------------------------------
__device__ __forceinline__ void bn_stats_body(
    const ushort_t* y, const float* gamma, const float* beta,
    float* scale, float* shift, int c, int tid, float kscale)
{
    float s = 0.f, s2 = 0.f;
    for (int b = 0; b < NB; ++b) {
        const uint4* p = (const uint4*)(y + ((size_t)b * CCH + c) * L);
        #pragma unroll
        for (int r = 0; r < 2; ++r) {
            uint4 v = p[r * 256 + tid];
            unsigned w[4] = {v.x, v.y, v.z, v.w};
            #pragma unroll
            for (int u = 0; u < 4; ++u) {
                float a = bflo(w[u]), bb = bfhi(w[u]);
                s  += a + bb;
                s2 += a * a + bb * bb;
            }
        }
    }
    #pragma unroll
    for (int off = 32; off > 0; off >>= 1) {
        s  += __shfl_down(s, off);
        s2 += __shfl_down(s2, off);
    }
    __shared__ float red[2][4];
    if ((tid & 63) == 0) { red[0][tid >> 6] = s; red[1][tid >> 6] = s2; }
    __syncthreads();
    if (tid == 0) {
        float S  = red[0][0] + red[0][1] + red[0][2] + red[0][3];
        float S2 = red[1][0] + red[1][1] + red[1][2] + red[1][3];
        const float invN = 1.f / (NB * (float)L);
        float mean = S * invN;
        float var  = S2 * invN - mean * mean;
        float rstd = rsqrtf(var + 1e-5f);
        float g = gamma[c];
        scale[c] = kscale * g * rstd;
        shift[c] = kscale * (beta[c] - mean * g * rstd);
    }
}

// two tensors in one launch: blockIdx.x in [0,512). K channel gets log2e fold.
__global__ __launch_bounds__(256) void bn_stats2_k(
    const ushort_t* __restrict__ y1, const float* __restrict__ g1, const float* __restrict__ be1,
    float* __restrict__ sc1, float* __restrict__ sh1,
    const ushort_t* __restrict__ y2, const float* __restrict__ g2, const float* __restrict__ be2,
    float* __restrict__ sc2, float* __restrict__ sh2)
{
    const int c = blockIdx.x & 255;
    if (blockIdx.x < 256) bn_stats_body(y1, g1, be1, sc1, sh1, c, threadIdx.x, LOG2E);
    else                  bn_stats_body(y2, g2, be2, sc2, sh2, c, threadIdx.x, 1.0f);
}

// ---------------------------------------------------------------------------
// Attention v4: single fused phase. For each window we compute the 9
// exponentials ONCE, normalize with rcp(S), multiply by the staged x values
// and scatter-accumulate into a 16 KB f32 LDS ring via ds_add_f32
// (element f+j of the f-ring contributes to output (f+j) & 4095; windows
// tile the ring contiguously, lane-stride 9 floats -> conflict-free banks).
// Removes phase 2 entirely (half the exps, ~60% of the VALU, 216 LDS
// reads/thread) and the 32 KB sCI buffer (occupancy 2 -> 3 blocks/CU).
// ---------------------------------------------------------------------------
__global__ __launch_bounds__(512, 6) void attention_k(
    const float* __restrict__ x,
    const ushort_t* __restrict__ y1,
    const ushort_t* __restrict__ y2,
    const float* __restrict__ s1sc, const float* __restrict__ s1sh,
    const float* __restrict__ s2sc, const float* __restrict__ s2sh,
    ushort_t* __restrict__ pre)
{
    __shared__ unsigned sKQg[4240];   // [GOF+s] = packed bf16 (k', q); guards zero
    __shared__ ushort_t sXg [4240];   // [GOF+s] = bf16 x; guards zero
    __shared__ float    accF[L];      // output accumulator (16 KB)

    const int bc = blockIdx.x;
    const int tid = threadIdx.x;
    const int ch = bc & 255;
    const size_t off = (size_t)bc * L;

    const float sc1 = s1sc[ch], sh1 = s1sh[ch];   // pre-scaled by log2e
    const float sc2 = s2sc[ch], sh2 = s2sh[ch];

    // ---- stage + guards + zero accumulator ---------------------------
    if (tid < GOF)  { sKQg[tid] = 0; sXg[tid] = 0; }
    if (tid < 72)   { sKQg[GOF + 4096 + tid] = 0; sXg[GOF + 4096 + tid] = 0; }
    {
        float4 z = {0.f, 0.f, 0.f, 0.f};
        ((float4*)accF)[tid]       = z;
        ((float4*)accF)[tid + 512] = z;
    }
    {
        uint4 ak = ((const uint4*)(y1 + off))[tid];
        uint4 aq = ((const uint4*)(y2 + off))[tid];
        float4 xa = ((const float4*)(x + off))[2 * tid];
        float4 xb = ((const float4*)(x + off))[2 * tid + 1];
        unsigned wk[4] = {ak.x, ak.y, ak.z, ak.w};
        unsigned wq[4] = {aq.x, aq.y, aq.z, aq.w};
        unsigned kq[8];
        #pragma unroll
        for (int u = 0; u < 4; ++u) {
            float klo = fmaxf(fmaf(bflo(wk[u]), sc1, sh1), 0.f);
            float khi = fmaxf(fmaf(bfhi(wk[u]), sc1, sh1), 0.f);
            float qlo = fmaxf(fmaf(bflo(wq[u]), sc2, sh2), 0.f);
            float qhi = fmaxf(fmaf(bfhi(wq[u]), sc2, sh2), 0.f);
            kq[2*u]   = (unsigned)f2bf(klo) | ((unsigned)f2bf(qlo) << 16);
            kq[2*u+1] = (unsigned)f2bf(khi) | ((unsigned)f2bf(qhi) << 16);
        }
        *(uint4*)&sKQg[GOF + 8 * tid]     = make_uint4(kq[0], kq[1], kq[2], kq[3]);
        *(uint4*)&sKQg[GOF + 8 * tid + 4] = make_uint4(kq[4], kq[5], kq[6], kq[7]);
        float xv[8] = {xa.x, xa.y, xa.z, xa.w, xb.x, xb.y, xb.z, xb.w};
        unsigned xp[4];
        #pragma unroll
        for (int u = 0; u < 4; ++u)
            xp[u] = (unsigned)f2bf(xv[2*u]) | ((unsigned)f2bf(xv[2*u+1]) << 16);
        *(uint4*)&sXg[GOF + 8 * tid] = make_uint4(xp[0], xp[1], xp[2], xp[3]);
    }
    __syncthreads();

    // ---- fused per-window softmax + scatter-accumulate ---------------
    {
        const int fbase = 9 * tid;
        #pragma unroll
        for (int r = 0; r < 8; ++r) {
            const int f  = fbase + 4608 * r;       // f = 9 * window_index
            const int t  = f >> 12;
            const int fl = f & 4095;
            unsigned wv[9];
            float    xw[9];
            if (fl < 4088) {                       // fast path: single tap t
                const int di = (t * 86) >> 8;
                const int dj = t - 3 * di;
                const int cbad = (dj == 0) ? 0 : ((dj == 2) ? 63 : 99);
                const int base = fl + (di << 6) + dj - 65 + GOF;
                #pragma unroll
                for (int j = 0; j < 9; ++j) {
                    wv[j] = sKQg[base + j];
                    xw[j] = bfu(sXg[base + j]);
                }
                #pragma unroll
                for (int j = 0; j < 9; ++j) {
                    int c = (fl + j) & 63;
                    bool bad = (c == cbad);
                    wv[j] = bad ? 0u  : wv[j];
                    xw[j] = bad ? 0.f : xw[j];
                }
            } else {                               // straddle: generic decode
                #pragma unroll
                for (int j = 0; j < 9; ++j) {
                    int fj = f + j;
                    int tj = fj >> 12, lj = fj & 4095;
                    int dij = (tj * 86) >> 8, djj = tj - 3 * dij;
                    int idx = lj + (dij << 6) + djj - 65 + GOF;
                    unsigned wr = sKQg[idx];
                    float    xr = bfu(sXg[idx]);
                    int c = lj & 63;
                    int cb = (djj == 0) ? 0 : ((djj == 2) ? 63 : 99);
                    bool bad = (c == cb);
                    wv[j] = bad ? 0u  : wr;
                    xw[j] = bad ? 0.f : xr;
                }
            }
            const unsigned cw = wv[4];
            const float kc = bflo(cw), qc = bfhi(cw);
            float e[9];
            #pragma unroll
            for (int j = 0; j < 9; ++j)
                e[j] = __builtin_amdgcn_exp2f(bflo(wv[j]) * qc + kc * bfhi(wv[j]));
            float s = (((e[0] + e[1]) + (e[2] + e[3])) +
                       ((e[4] + e[5]) + (e[6] + e[7]))) + e[8];
            const float rinv = __builtin_amdgcn_rcpf(s);
            if (fl < 4088) {
                #pragma unroll
                for (int j = 0; j < 9; ++j)
                    atomicAdd(&accF[fl + j], e[j] * rinv * xw[j]);
            } else {
                #pragma unroll
                for (int j = 0; j < 9; ++j)
                    atomicAdd(&accF[(f + j) & 4095], e[j] * rinv * xw[j]);
            }
        }
    }
    __syncthreads();

    // ---- write out (pairs -> 4B/lane coalesced stores) ----------------
    {
        unsigned* po = (unsigned*)(pre + off);
        #pragma unroll
        for (int rr = 0; rr < 4; ++rr) {
            const int p = rr * 512 + tid;
            po[p] = pk_bf16(accF[2 * p], accF[2 * p + 1]);
        }
    }
}

// ---------------------------------------------------------------------------
// Fused final BN: per-channel stats + apply + ReLU in one kernel.
// Block c: stage channel's 4x4096 bf16 (32 KB LDS), reduce, finalize, apply.
// ---------------------------------------------------------------------------
__global__ __launch_bounds__(256) void bn_fused_k(
    const ushort_t* __restrict__ yf,
    const float* __restrict__ gf, const float* __restrict__ bef,
    float* __restrict__ out)
{
    __shared__ uint4 sY[2048];       // 4 batches x 512 uint4 = 32 KB
    __shared__ float red[2][4];
    __shared__ float fsc, fsh;

    const int c = blockIdx.x, tid = threadIdx.x;
    float s = 0.f, s2 = 0.f;
    #pragma unroll
    for (int b = 0; b < NB; ++b) {
        const uint4* p = (const uint4*)(yf + ((size_t)b * CCH + c) * L);
        #pragma unroll
        for (int r = 0; r < 2; ++r) {
            uint4 v = p[r * 256 + tid];
            sY[b * 512 + r * 256 + tid] = v;
            unsigned w[4] = {v.x, v.y, v.z, v.w};
            #pragma unroll
            for (int u = 0; u < 4; ++u) {
                float a = bflo(w[u]), bb = bfhi(w[u]);
                s  += a + bb;
                s2 += a * a + bb * bb;
            }
        }
    }
    #pragma unroll
    for (int off = 32; off > 0; off >>= 1) {
        s  += __shfl_down(s, off);
        s2 += __shfl_down(s2, off);
    }
    if ((tid & 63) == 0) { red[0][tid >> 6] = s; red[1][tid >> 6] = s2; }
    __syncthreads();
    if (tid == 0) {
        float S  = red[0][0] + red[0][1] + red[0][2] + red[0][3];
        float S2 = red[1][0] + red[1][1] + red[1][2] + red[1][3];
        const float invN = 1.f / (NB * (float)L);
        float mean = S * invN;
        float var  = S2 * invN - mean * mean;
        float rstd = rsqrtf(var + 1e-5f);
        float g = gf[c];
        fsc = g * rstd;
        fsh = bef[c] - mean * g * rstd;
    }
    __syncthreads();
    const float sc = fsc, sh = fsh;

    #pragma unroll
    for (int b = 0; b < NB; ++b) {
        float4* o = (float4*)(out + ((size_t)b * CCH + c) * L);
        #pragma unroll
        for (int r = 0; r < 2; ++r) {
            uint4 v = sY[b * 512 + r * 256 + tid];
            unsigned w[4] = {v.x, v.y, v.z, v.w};
            float4 o0, o1;
            o0.x = fmaxf(fmaf(bflo(w[0]), sc, sh), 0.f);
            o0.y = fmaxf(fmaf(bfhi(w[0]), sc, sh), 0.f);
            o0.z = fmaxf(fmaf(bflo(w[1]), sc, sh), 0.f);
            o0.w = fmaxf(fmaf(bfhi(w[1]), sc, sh), 0.f);
            o1.x = fmaxf(fmaf(bflo(w[2]), sc, sh), 0.f);
            o1.y = fmaxf(fmaf(bfhi(w[2]), sc, sh), 0.f);
            o1.z = fmaxf(fmaf(bflo(w[3]), sc, sh), 0.f);
            o1.w = fmaxf(fmaf(bfhi(w[3]), sc, sh), 0.f);
            int i = r * 256 + tid;
            o[2 * i]     = o0;
            o[2 * i + 1] = o1;
        }
    }
}

// ---------------------------------------------------------------------------
extern "C" void kernel_launch(void* const* d_in, const int* in_sizes, int n_in,
                              void* d_out, int out_size, void* d_ws, size_t ws_size,
                              hipStream_t stream) {
    const float* x   = (const float*)d_in[0];
    const float* w1  = (const float*)d_in[1];
    const float* b1  = (const float*)d_in[2];
    const float* g1  = (const float*)d_in[3];
    const float* be1 = (const float*)d_in[4];
    const float* w2  = (const float*)d_in[5];
    const float* b2  = (const float*)d_in[6];
    const float* g2  = (const float*)d_in[7];
    const float* be2 = (const float*)d_in[8];
    const float* wf  = (const float*)d_in[9];
    const float* bf  = (const float*)d_in[10];
    const float* gf  = (const float*)d_in[11];
    const float* bef = (const float*)d_in[12];
    float* out = (float*)d_out;

    const size_t NEL = (size_t)NB * CCH * L;       // 4194304
    ushort_t* y1b = (ushort_t*)d_ws;               // conv1 out (bf16); later yf
    ushort_t* y2b = y1b + NEL;                     // conv2 out (bf16); later pre
    float* st = (float*)(y2b + NEL);               // stats: 4 x 256
    float* s1sc = st,        *s1sh = st + 256;
    float* s2sc = st + 512,  *s2sh = st + 768;
    ushort_t* wb1 = (ushort_t*)(st + 1536);        // bf16 weights: 3 x 64K
    ushort_t* wb2 = wb1 + CCH * CCH;
    ushort_t* wbf = wb2 + CCH * CCH;

    wcvt_k<<<192, 256, 0, stream>>>(w1, w2, wf, wb1, wb2, wbf);
    dim3 gg(64, 2, 4);
    dual_gemm_k<<<gg, 256, 0, stream>>>(x, wb1, b1, wb2, b2, y1b, y2b);
    bn_stats2_k<<<512, 256, 0, stream>>>(y1b, g1, be1, s1sc, s1sh,
                                         y2b, g2, be2, s2sc, s2sh);
    attention_k<<<NB * CCH, 512, 0, stream>>>(x, y1b, y2b,
                                              s1sc, s1sh, s2sc, s2sh,
                                              /*pre=*/y2b);
    single_gemm_k<<<gg, 256, 0, stream>>>(/*pre=*/y2b, wbf, bf, /*yf=*/y1b);
    bn_fused_k<<<256, 256, 0, stream>>>(y1b, gf, bef, out);
}

// Round 3
// 161.411 us; speedup vs baseline: 2.0356x; 2.0356x over previous
//
#include <hip/hip_runtime.h>
#include <hip/hip_bf16.h>

#define L 4096
#define CCH 256
#define NB 4
#define KP 40   // padded LDS row length (32 k + 8 pad) in bf16 elems; 80 B rows
#define GOF 72  // guarded-image front offset (alignment-friendly, >= 65)
#define LOG2E 1.4426950408889634f

typedef __attribute__((ext_vector_type(8))) short short8;
typedef __attribute__((ext_vector_type(4))) float f32x4;
typedef unsigned short ushort_t;

__device__ __forceinline__ unsigned short f2bf(float f) {
    unsigned u = __builtin_bit_cast(unsigned, f);
    u += 0x7FFF + ((u >> 16) & 1);
    return (unsigned short)(u >> 16);
}
// packed RNE f32x2 -> bf16x2; kept in GEMM epilogues / staging
__device__ __forceinline__ unsigned pk_bf16(float a, float b) {
    __hip_bfloat162 h = __float22bfloat162_rn(make_float2(a, b));
    unsigned u;
    __builtin_memcpy(&u, &h, 4);
    return u;
}
__device__ __forceinline__ float bflo(unsigned w) {
    return __builtin_bit_cast(float, w << 16);
}
__device__ __forceinline__ float bfhi(unsigned w) {
    return __builtin_bit_cast(float, w & 0xFFFF0000u);
}
__device__ __forceinline__ float bfu(ushort_t h) {
    return __builtin_bit_cast(float, (unsigned)h << 16);
}

// ---------------------------------------------------------------------------
// One-time weight conversion: w1|w2|wf (each 256x256 f32) -> bf16
// ---------------------------------------------------------------------------
__global__ __launch_bounds__(256) void wcvt_k(
    const float* __restrict__ w1, const float* __restrict__ w2,
    const float* __restrict__ wf,
    ushort_t* __restrict__ wb1, ushort_t* __restrict__ wb2,
    ushort_t* __restrict__ wbf)
{
    const int mb = blockIdx.x >> 6;          // 0..2: which matrix
    const int i  = (blockIdx.x & 63) * 256 + threadIdx.x;   // float4 index
    const float* src = (mb == 0) ? w1 : (mb == 1) ? w2 : wf;
    ushort_t*    dst = (mb == 0) ? wb1 : (mb == 1) ? wb2 : wbf;
    float4 v = ((const float4*)src)[i];
    uint2 p;
    p.x = pk_bf16(v.x, v.y);
    p.y = pk_bf16(v.z, v.w);
    ((uint2*)dst)[i] = p;
}

// ---------------------------------------------------------------------------
// Dual conv1x1 via bf16 MFMA (unchanged R13)
// ---------------------------------------------------------------------------
__global__ __launch_bounds__(256, 2) void dual_gemm_k(
    const float* __restrict__ x,
    const ushort_t* __restrict__ wb1, const float* __restrict__ b1,
    const ushort_t* __restrict__ wb2, const float* __restrict__ b2,
    ushort_t* __restrict__ y1, ushort_t* __restrict__ y2)
{
    __shared__ short sA1[128 * KP];
    __shared__ short sA2[128 * KP];
    __shared__ short sB [64 * KP];

    const int tid = threadIdx.x;
    const int l0 = blockIdx.x * 64;
    const int o0 = blockIdx.y * 128;
    const int b  = blockIdx.z;

    const int wv = tid >> 6;
    const int lane = tid & 63;
    const int m = lane & 15;
    const int quad = lane >> 4;

    const float* xb = x + (size_t)b * CCH * L;

    const int sl = tid & 63, soct = tid >> 6;
    const int sr = tid & 127, sh = tid >> 7;

    f32x4 acc1[2][4], acc2[2][4];
    #pragma unroll
    for (int io = 0; io < 2; ++io)
        #pragma unroll
        for (int jl = 0; jl < 4; ++jl) {
            acc1[io][jl] = (f32x4){0.f,0.f,0.f,0.f};
            acc2[io][jl] = (f32x4){0.f,0.f,0.f,0.f};
        }

    for (int s = 0; s < 8; ++s) {
        const int k0 = s * 32;
        __syncthreads();
        {
            const float* xs = xb + (size_t)(k0 + soct * 8) * L + l0 + sl;
            float f[8];
            #pragma unroll
            for (int j = 0; j < 8; ++j) f[j] = xs[(size_t)j * L];
            uint4 v;
            v.x = pk_bf16(f[0], f[1]);
            v.y = pk_bf16(f[2], f[3]);
            v.z = pk_bf16(f[4], f[5]);
            v.w = pk_bf16(f[6], f[7]);
            *(uint4*)&sB[sl * KP + soct * 8] = v;
        }
        {
            const uint4* wp = (const uint4*)&wb1[(size_t)(o0 + sr) * CCH + k0 + sh * 16];
            uint4 p0 = wp[0], p1 = wp[1];
            *(uint4*)&sA1[sr * KP + sh * 16]     = p0;
            *(uint4*)&sA1[sr * KP + sh * 16 + 8] = p1;
            const uint4* wq = (const uint4*)&wb2[(size_t)(o0 + sr) * CCH + k0 + sh * 16];
            uint4 q0 = wq[0], q1 = wq[1];
            *(uint4*)&sA2[sr * KP + sh * 16]     = q0;
            *(uint4*)&sA2[sr * KP + sh * 16 + 8] = q1;
        }
        __syncthreads();
        short8 a1[2], a2[2], bf[4];
        #pragma unroll
        for (int io = 0; io < 2; ++io) {
            a1[io] = *(const short8*)&sA1[(wv * 32 + io * 16 + m) * KP + quad * 8];
            a2[io] = *(const short8*)&sA2[(wv * 32 + io * 16 + m) * KP + quad * 8];
        }
        #pragma unroll
        for (int jl = 0; jl < 4; ++jl)
            bf[jl] = *(const short8*)&sB[(jl * 16 + m) * KP + quad * 8];
        #pragma unroll
        for (int io = 0; io < 2; ++io)
            #pragma unroll
            for (int jl = 0; jl < 4; ++jl) {
                acc1[io][jl] = __builtin_amdgcn_mfma_f32_16x16x32_bf16(a1[io], bf[jl], acc1[io][jl], 0, 0, 0);
                acc2[io][jl] = __builtin_amdgcn_mfma_f32_16x16x32_bf16(a2[io], bf[jl], acc2[io][jl], 0, 0, 0);
            }
    }

    #pragma unroll
    for (int io = 0; io < 2; ++io)
        #pragma unroll
        for (int reg = 0; reg < 4; ++reg) {
            const int o = o0 + wv * 32 + io * 16 + quad * 4 + reg;
            const float bb1 = b1[o], bb2 = b2[o];
            const size_t ro = ((size_t)b * CCH + o) * L + l0 + m;
            unsigned u1a = pk_bf16(acc1[io][0][reg] + bb1, acc1[io][1][reg] + bb1);
            unsigned u1b = pk_bf16(acc1[io][2][reg] + bb1, acc1[io][3][reg] + bb1);
            unsigned u2a = pk_bf16(acc2[io][0][reg] + bb2, acc2[io][1][reg] + bb2);
            unsigned u2b = pk_bf16(acc2[io][2][reg] + bb2, acc2[io][3][reg] + bb2);
            y1[ro]      = (ushort_t)u1a;
            y1[ro + 16] = (ushort_t)(u1a >> 16);
            y1[ro + 32] = (ushort_t)u1b;
            y1[ro + 48] = (ushort_t)(u1b >> 16);
            y2[ro]      = (ushort_t)u2a;
            y2[ro + 16] = (ushort_t)(u2a >> 16);
            y2[ro + 32] = (ushort_t)u2b;
            y2[ro + 48] = (ushort_t)(u2b >> 16);
        }
}

// ---------------------------------------------------------------------------
// Single conv1x1 via bf16 MFMA (unchanged R13)
// ---------------------------------------------------------------------------
__global__ __launch_bounds__(256, 2) void single_gemm_k(
    const ushort_t* __restrict__ x,
    const ushort_t* __restrict__ wb, const float* __restrict__ bb,
    ushort_t* __restrict__ y)
{
    __shared__ short sA[128 * KP];
    __shared__ short sB[64 * KP];

    const int tid = threadIdx.x;
    const int l0 = blockIdx.x * 64;
    const int o0 = blockIdx.y * 128;
    const int b  = blockIdx.z;

    const int wv = tid >> 6;
    const int lane = tid & 63;
    const int m = lane & 15;
    const int quad = lane >> 4;

    const ushort_t* xb = x + (size_t)b * CCH * L;

    const int sl = tid & 63, soct = tid >> 6;
    const int sr = tid & 127, sh = tid >> 7;

    f32x4 acc[2][4];
    #pragma unroll
    for (int io = 0; io < 2; ++io)
        #pragma unroll
        for (int jl = 0; jl < 4; ++jl)
            acc[io][jl] = (f32x4){0.f,0.f,0.f,0.f};

    for (int s = 0; s < 8; ++s) {
        const int k0 = s * 32;
        __syncthreads();
        {
            const ushort_t* xs = xb + (size_t)(k0 + soct * 8) * L + l0 + sl;
            short8 v;
            #pragma unroll
            for (int j = 0; j < 8; ++j) v[j] = (short)xs[(size_t)j * L];
            *(short8*)&sB[sl * KP + soct * 8] = v;
        }
        {
            const uint4* wp = (const uint4*)&wb[(size_t)(o0 + sr) * CCH + k0 + sh * 16];
            uint4 p0 = wp[0], p1 = wp[1];
            *(uint4*)&sA[sr * KP + sh * 16]     = p0;
            *(uint4*)&sA[sr * KP + sh * 16 + 8] = p1;
        }
        __syncthreads();
        short8 a[2], bf[4];
        #pragma unroll
        for (int io = 0; io < 2; ++io)
            a[io] = *(const short8*)&sA[(wv * 32 + io * 16 + m) * KP + quad * 8];
        #pragma unroll
        for (int jl = 0; jl < 4; ++jl)
            bf[jl] = *(const short8*)&sB[(jl * 16 + m) * KP + quad * 8];
        #pragma unroll
        for (int io = 0; io < 2; ++io)
            #pragma unroll
            for (int jl = 0; jl < 4; ++jl)
                acc[io][jl] = __builtin_amdgcn_mfma_f32_16x16x32_bf16(a[io], bf[jl], acc[io][jl], 0, 0, 0);
    }

    #pragma unroll
    for (int io = 0; io < 2; ++io)
        #pragma unroll
        for (int reg = 0; reg < 4; ++reg) {
            const int o = o0 + wv * 32 + io * 16 + quad * 4 + reg;
            const float b0 = bb[o];
            const size_t ro = ((size_t)b * CCH + o) * L + l0 + m;
            unsigned ua = pk_bf16(acc[io][0][reg] + b0, acc[io][1][reg] + b0);
            unsigned ub = pk_bf16(acc[io][2][reg] + b0, acc[io][3][reg] + b0);
            y[ro]      = (ushort_t)ua;
            y[ro + 16] = (ushort_t)(ua >> 16);
            y[ro + 32] = (ushort_t)ub;
            y[ro + 48] = (ushort_t)(ub >> 16);
        }
}

// ---------------------------------------------------------------------------
// BatchNorm stats over bf16 tensor -> finalized scale/shift.
// kscale: extra factor folded into scale/shift (log2e for the K channel).
// ---------------------------------------------------------------------------
__device__ __forceinline__ void bn_stats_body(
    const ushort_t* y, const float* gamma, const float* beta,
    float* scale, float* shift, int c, int tid, float kscale)
{
    float s = 0.f, s2 = 0.f;
    for (int b = 0; b < NB; ++b) {
        const uint4* p = (const uint4*)(y + ((size_t)b * CCH + c) * L);
        #pragma unroll
        for (int r = 0; r < 2; ++r) {
            uint4 v = p[r * 256 + tid];
            unsigned w[4] = {v.x, v.y, v.z, v.w};
            #pragma unroll
            for (int u = 0; u < 4; ++u) {
                float a = bflo(w[u]), bb = bfhi(w[u]);
                s  += a + bb;
                s2 += a * a + bb * bb;
            }
        }
    }
    #pragma unroll
    for (int off = 32; off > 0; off >>= 1) {
        s  += __shfl_down(s, off);
        s2 += __shfl_down(s2, off);
    }
    __shared__ float red[2][4];
    if ((tid & 63) == 0) { red[0][tid >> 6] = s; red[1][tid >> 6] = s2; }
    __syncthreads();
    if (tid == 0) {
        float S  = red[0][0] + red[0][1] + red[0][2] + red[0][3];
        float S2 = red[1][0] + red[1][1] + red[1][2] + red[1][3];
        const float invN = 1.f / (NB * (float)L);
        float mean = S * invN;
        float var  = S2 * invN - mean * mean;
        float rstd = rsqrtf(var + 1e-5f);
        float g = gamma[c];
        scale[c] = kscale * g * rstd;
        shift[c] = kscale * (beta[c] - mean * g * rstd);
    }
}

// two tensors in one launch: blockIdx.x in [0,512). K channel gets log2e fold.
__global__ __launch_bounds__(256) void bn_stats2_k(
    const ushort_t* __restrict__ y1, const float* __restrict__ g1, const float* __restrict__ be1,
    float* __restrict__ sc1, float* __restrict__ sh1,
    const ushort_t* __restrict__ y2, const float* __restrict__ g2, const float* __restrict__ be2,
    float* __restrict__ sc2, float* __restrict__ sh2)
{
    const int c = blockIdx.x & 255;
    if (blockIdx.x < 256) bn_stats_body(y1, g1, be1, sc1, sh1, c, threadIdx.x, LOG2E);
    else                  bn_stats_body(y2, g2, be2, sc2, sh2, c, threadIdx.x, 1.0f);
}

// ---------------------------------------------------------------------------
// Attention v6: fused single-pass (R1's VERIFIED compute — passed absmax
// 0.03125) with race-free manual LDS read-modify-write instead of atomics.
// R1 lesson: atomicAdd(__shared__ float*) = CAS loop, serial rtn-waits, 4x
// slower. Here: per r-iteration, contributions go to registers, then two
// barrier-separated write sub-phases (tid<455 | tid>=455). Collision
// analysis: thread tid's 9-elem flat run [9(tid+512r), +9) aliases mod 4096
// only at dtid in {455,456} (|9*455-4096|=1, |9*456-4096|=8); sub-phase A
// has max dtid 454, B has max 56 -> no aliasing within a sub-phase; cross-
// iteration pairs (dtid in {-57,-56}) are separated by >=1 barrier.
// LDS = 16960+8480+16384 = 41824 B -> 3 blocks/CU (was 2 at 58368).
// Halves exps (72 vs 144/thr) and VALU vs the two-phase version.
// ---------------------------------------------------------------------------
__global__ __launch_bounds__(512, 6) void attention_k(
    const float* __restrict__ x,
    const ushort_t* __restrict__ y1,
    const ushort_t* __restrict__ y2,
    const float* __restrict__ s1sc, const float* __restrict__ s1sh,
    const float* __restrict__ s2sc, const float* __restrict__ s2sh,
    ushort_t* __restrict__ pre)
{
    __shared__ unsigned sKQg[4240];   // [GOF+s] = packed bf16 (k', q); guards zero
    __shared__ ushort_t sXg [4240];   // [GOF+s] = bf16 x; guards zero
    __shared__ float    accF[L];      // output accumulator (16 KB)

    const int bc = blockIdx.x;
    const int tid = threadIdx.x;
    const int ch = bc & 255;
    const size_t off = (size_t)bc * L;

    const float sc1 = s1sc[ch], sh1 = s1sh[ch];   // pre-scaled by log2e
    const float sc2 = s2sc[ch], sh2 = s2sh[ch];

    // ---- stage + guards + zero accumulator ---------------------------
    if (tid < GOF)  { sKQg[tid] = 0; sXg[tid] = 0; }
    if (tid < 72)   { sKQg[GOF + 4096 + tid] = 0; sXg[GOF + 4096 + tid] = 0; }
    {
        float4 z = {0.f, 0.f, 0.f, 0.f};
        ((float4*)accF)[tid]       = z;
        ((float4*)accF)[tid + 512] = z;
    }
    {
        uint4 ak = ((const uint4*)(y1 + off))[tid];
        uint4 aq = ((const uint4*)(y2 + off))[tid];
        float4 xa = ((const float4*)(x + off))[2 * tid];
        float4 xb = ((const float4*)(x + off))[2 * tid + 1];
        unsigned wk[4] = {ak.x, ak.y, ak.z, ak.w};
        unsigned wq[4] = {aq.x, aq.y, aq.z, aq.w};
        unsigned kq[8];
        #pragma unroll
        for (int u = 0; u < 4; ++u) {
            float klo = fmaxf(fmaf(bflo(wk[u]), sc1, sh1), 0.f);
            float khi = fmaxf(fmaf(bfhi(wk[u]), sc1, sh1), 0.f);
            float qlo = fmaxf(fmaf(bflo(wq[u]), sc2, sh2), 0.f);
            float qhi = fmaxf(fmaf(bfhi(wq[u]), sc2, sh2), 0.f);
            kq[2*u]   = (unsigned)f2bf(klo) | ((unsigned)f2bf(qlo) << 16);
            kq[2*u+1] = (unsigned)f2bf(khi) | ((unsigned)f2bf(qhi) << 16);
        }
        *(uint4*)&sKQg[GOF + 8 * tid]     = make_uint4(kq[0], kq[1], kq[2], kq[3]);
        *(uint4*)&sKQg[GOF + 8 * tid + 4] = make_uint4(kq[4], kq[5], kq[6], kq[7]);
        float xv[8] = {xa.x, xa.y, xa.z, xa.w, xb.x, xb.y, xb.z, xb.w};
        unsigned xp[4];
        #pragma unroll
        for (int u = 0; u < 4; ++u)
            xp[u] = (unsigned)f2bf(xv[2*u]) | ((unsigned)f2bf(xv[2*u+1]) << 16);
        *(uint4*)&sXg[GOF + 8 * tid] = make_uint4(xp[0], xp[1], xp[2], xp[3]);
    }
    __syncthreads();

    // ---- fused per-window softmax + phased scatter-accumulate ---------
    {
        const int fbase = 9 * tid;
        #pragma unroll
        for (int r = 0; r < 8; ++r) {
            const int f  = fbase + 4608 * r;       // f = 9 * window_index
            const int t  = f >> 12;
            const int fl = f & 4095;
            unsigned wv[9];
            float    xw[9];
            const bool fastp = (fl < 4088);
            if (fastp) {                           // fast path: single tap t
                const int di = (t * 86) >> 8;
                const int dj = t - 3 * di;
                const int cbad = (dj == 0) ? 0 : ((dj == 2) ? 63 : 99);
                const int base = fl + (di << 6) + dj - 65 + GOF;
                #pragma unroll
                for (int j = 0; j < 9; ++j) {
                    wv[j] = sKQg[base + j];
                    xw[j] = bfu(sXg[base + j]);
                }
                #pragma unroll
                for (int j = 0; j < 9; ++j) {
                    int c = (fl + j) & 63;
                    bool bad = (c == cbad);
                    wv[j] = bad ? 0u  : wv[j];
                    xw[j] = bad ? 0.f : xw[j];
                }
            } else {                               // straddle: generic decode
                #pragma unroll
                for (int j = 0; j < 9; ++j) {
                    int fj = f + j;
                    int tj = fj >> 12, lj = fj & 4095;
                    int dij = (tj * 86) >> 8, djj = tj - 3 * dij;
                    int idx = lj + (dij << 6) + djj - 65 + GOF;
                    unsigned wr = sKQg[idx];
                    float    xr = bfu(sXg[idx]);
                    int c = lj & 63;
                    int cb = (djj == 0) ? 0 : ((djj == 2) ? 63 : 99);
                    bool bad = (c == cb);
                    wv[j] = bad ? 0u  : wr;
                    xw[j] = bad ? 0.f : xr;
                }
            }
            const unsigned cw = wv[4];
            const float kc = bflo(cw), qc = bfhi(cw);
            float e[9];
            #pragma unroll
            for (int j = 0; j < 9; ++j)
                e[j] = __builtin_amdgcn_exp2f(bflo(wv[j]) * qc + kc * bfhi(wv[j]));
            float s = (((e[0] + e[1]) + (e[2] + e[3])) +
                       ((e[4] + e[5]) + (e[6] + e[7]))) + e[8];
            const float rinv = __builtin_amdgcn_rcpf(s);
            float cj[9];
            #pragma unroll
            for (int j = 0; j < 9; ++j)
                cj[j] = e[j] * rinv * xw[j];

            // phased race-free RMW (see header comment)
            __syncthreads();
            if (tid < 455) {
                if (fastp) {
                    #pragma unroll
                    for (int j = 0; j < 9; ++j) accF[fl + j] += cj[j];
                } else {
                    #pragma unroll
                    for (int j = 0; j < 9; ++j) accF[(f + j) & 4095] += cj[j];
                }
            }
            __syncthreads();
            if (tid >= 455) {
                if (fastp) {
                    #pragma unroll
                    for (int j = 0; j < 9; ++j) accF[fl + j] += cj[j];
                } else {
                    #pragma unroll
                    for (int j = 0; j < 9; ++j) accF[(f + j) & 4095] += cj[j];
                }
            }
        }
    }
    __syncthreads();

    // ---- write out (pairs -> 4B/lane coalesced stores) ----------------
    {
        unsigned* po = (unsigned*)(pre + off);
        #pragma unroll
        for (int rr = 0; rr < 4; ++rr) {
            const int p = rr * 512 + tid;
            po[p] = pk_bf16(accF[2 * p], accF[2 * p + 1]);
        }
    }
}

// ---------------------------------------------------------------------------
// Fused final BN: per-channel stats + apply + ReLU in one kernel.
// Block c: stage channel's 4x4096 bf16 (32 KB LDS), reduce, finalize, apply.
// ---------------------------------------------------------------------------
__global__ __launch_bounds__(256) void bn_fused_k(
    const ushort_t* __restrict__ yf,
    const float* __restrict__ gf, const float* __restrict__ bef,
    float* __restrict__ out)
{
    __shared__ uint4 sY[2048];       // 4 batches x 512 uint4 = 32 KB
    __shared__ float red[2][4];
    __shared__ float fsc, fsh;

    const int c = blockIdx.x, tid = threadIdx.x;
    float s = 0.f, s2 = 0.f;
    #pragma unroll
    for (int b = 0; b < NB; ++b) {
        const uint4* p = (const uint4*)(yf + ((size_t)b * CCH + c) * L);
        #pragma unroll
        for (int r = 0; r < 2; ++r) {
            uint4 v = p[r * 256 + tid];
            sY[b * 512 + r * 256 + tid] = v;
            unsigned w[4] = {v.x, v.y, v.z, v.w};
            #pragma unroll
            for (int u = 0; u < 4; ++u) {
                float a = bflo(w[u]), bb = bfhi(w[u]);
                s  += a + bb;
                s2 += a * a + bb * bb;
            }
        }
    }
    #pragma unroll
    for (int off = 32; off > 0; off >>= 1) {
        s  += __shfl_down(s, off);
        s2 += __shfl_down(s2, off);
    }
    if ((tid & 63) == 0) { red[0][tid >> 6] = s; red[1][tid >> 6] = s2; }
    __syncthreads();
    if (tid == 0) {
        float S  = red[0][0] + red[0][1] + red[0][2] + red[0][3];
        float S2 = red[1][0] + red[1][1] + red[1][2] + red[1][3];
        const float invN = 1.f / (NB * (float)L);
        float mean = S * invN;
        float var  = S2 * invN - mean * mean;
        float rstd = rsqrtf(var + 1e-5f);
        float g = gf[c];
        fsc = g * rstd;
        fsh = bef[c] - mean * g * rstd;
    }
    __syncthreads();
    const float sc = fsc, sh = fsh;

    #pragma unroll
    for (int b = 0; b < NB; ++b) {
        float4* o = (float4*)(out + ((size_t)b * CCH + c) * L);
        #pragma unroll
        for (int r = 0; r < 2; ++r) {
            uint4 v = sY[b * 512 + r * 256 + tid];
            unsigned w[4] = {v.x, v.y, v.z, v.w};
            float4 o0, o1;
            o0.x = fmaxf(fmaf(bflo(w[0]), sc, sh), 0.f);
            o0.y = fmaxf(fmaf(bfhi(w[0]), sc, sh), 0.f);
            o0.z = fmaxf(fmaf(bflo(w[1]), sc, sh), 0.f);
            o0.w = fmaxf(fmaf(bfhi(w[1]), sc, sh), 0.f);
            o1.x = fmaxf(fmaf(bflo(w[2]), sc, sh), 0.f);
            o1.y = fmaxf(fmaf(bfhi(w[2]), sc, sh), 0.f);
            o1.z = fmaxf(fmaf(bflo(w[3]), sc, sh), 0.f);
            o1.w = fmaxf(fmaf(bfhi(w[3]), sc, sh), 0.f);
            int i = r * 256 + tid;
            o[2 * i]     = o0;
            o[2 * i + 1] = o1;
        }
    }
}

// ---------------------------------------------------------------------------
extern "C" void kernel_launch(void* const* d_in, const int* in_sizes, int n_in,
                              void* d_out, int out_size, void* d_ws, size_t ws_size,
                              hipStream_t stream) {
    const float* x   = (const float*)d_in[0];
    const float* w1  = (const float*)d_in[1];
    const float* b1  = (const float*)d_in[2];
    const float* g1  = (const float*)d_in[3];
    const float* be1 = (const float*)d_in[4];
    const float* w2  = (const float*)d_in[5];
    const float* b2  = (const float*)d_in[6];
    const float* g2  = (const float*)d_in[7];
    const float* be2 = (const float*)d_in[8];
    const float* wf  = (const float*)d_in[9];
    const float* bf  = (const float*)d_in[10];
    const float* gf  = (const float*)d_in[11];
    const float* bef = (const float*)d_in[12];
    float* out = (float*)d_out;

    const size_t NEL = (size_t)NB * CCH * L;       // 4194304
    ushort_t* y1b = (ushort_t*)d_ws;               // conv1 out (bf16); later yf
    ushort_t* y2b = y1b + NEL;                     // conv2 out (bf16); later pre
    float* st = (float*)(y2b + NEL);               // stats: 4 x 256
    float* s1sc = st,        *s1sh = st + 256;
    float* s2sc = st + 512,  *s2sh = st + 768;
    ushort_t* wb1 = (ushort_t*)(st + 1536);        // bf16 weights: 3 x 64K
    ushort_t* wb2 = wb1 + CCH * CCH;
    ushort_t* wbf = wb2 + CCH * CCH;

    wcvt_k<<<192, 256, 0, stream>>>(w1, w2, wf, wb1, wb2, wbf);
    dim3 gg(64, 2, 4);
    dual_gemm_k<<<gg, 256, 0, stream>>>(x, wb1, b1, wb2, b2, y1b, y2b);
    bn_stats2_k<<<512, 256, 0, stream>>>(y1b, g1, be1, s1sc, s1sh,
                                         y2b, g2, be2, s2sc, s2sh);
    attention_k<<<NB * CCH, 512, 0, stream>>>(x, y1b, y2b,
                                              s1sc, s1sh, s2sc, s2sh,
                                              /*pre=*/y2b);
    single_gemm_k<<<gg, 256, 0, stream>>>(/*pre=*/y2b, wbf, bf, /*yf=*/y1b);
    bn_fused_k<<<256, 256, 0, stream>>>(y1b, gf, bef, out);
}

// Round 4
// 160.678 us; speedup vs baseline: 2.0448x; 1.0046x over previous
//
#include <hip/hip_runtime.h>
#include <hip/hip_bf16.h>

#define L 4096
#define CCH 256
#define NB 4
#define KP 40   // padded LDS row length (32 k + 8 pad) in bf16 elems; 80 B rows
#define GOF 72  // guarded-image front offset (alignment-friendly, >= 65)
#define LOG2E 1.4426950408889634f

typedef __attribute__((ext_vector_type(8))) short short8;
typedef __attribute__((ext_vector_type(4))) float f32x4;
typedef unsigned short ushort_t;

__device__ __forceinline__ unsigned short f2bf(float f) {
    unsigned u = __builtin_bit_cast(unsigned, f);
    u += 0x7FFF + ((u >> 16) & 1);
    return (unsigned short)(u >> 16);
}
// packed RNE f32x2 -> bf16x2; kept in GEMM epilogues / staging
__device__ __forceinline__ unsigned pk_bf16(float a, float b) {
    __hip_bfloat162 h = __float22bfloat162_rn(make_float2(a, b));
    unsigned u;
    __builtin_memcpy(&u, &h, 4);
    return u;
}
__device__ __forceinline__ float bflo(unsigned w) {
    return __builtin_bit_cast(float, w << 16);
}
__device__ __forceinline__ float bfhi(unsigned w) {
    return __builtin_bit_cast(float, w & 0xFFFF0000u);
}
__device__ __forceinline__ float bfu(ushort_t h) {
    return __builtin_bit_cast(float, (unsigned)h << 16);
}

// ---------------------------------------------------------------------------
// One-time weight conversion: w1|w2|wf (each 256x256 f32) -> bf16
// ---------------------------------------------------------------------------
__global__ __launch_bounds__(256) void wcvt_k(
    const float* __restrict__ w1, const float* __restrict__ w2,
    const float* __restrict__ wf,
    ushort_t* __restrict__ wb1, ushort_t* __restrict__ wb2,
    ushort_t* __restrict__ wbf)
{
    const int mb = blockIdx.x >> 6;          // 0..2: which matrix
    const int i  = (blockIdx.x & 63) * 256 + threadIdx.x;   // float4 index
    const float* src = (mb == 0) ? w1 : (mb == 1) ? w2 : wf;
    ushort_t*    dst = (mb == 0) ? wb1 : (mb == 1) ? wb2 : wbf;
    float4 v = ((const float4*)src)[i];
    uint2 p;
    p.x = pk_bf16(v.x, v.y);
    p.y = pk_bf16(v.z, v.w);
    ((uint2*)dst)[i] = p;
}

// ---------------------------------------------------------------------------
// Dual conv1x1 via bf16 MFMA — v2: double-buffered LDS + register prefetch.
// One barrier per k-step (was two); tile s+1's global loads are issued
// BEFORE tile s's MFMAs so HBM/L2 latency hides under compute + other waves.
// LDS 2x25.6 KB = 51.2 KB -> 3 blocks/CU at __launch_bounds__(256,3).
// ---------------------------------------------------------------------------
__global__ __launch_bounds__(256, 3) void dual_gemm_k(
    const float* __restrict__ x,
    const ushort_t* __restrict__ wb1, const float* __restrict__ b1,
    const ushort_t* __restrict__ wb2, const float* __restrict__ b2,
    ushort_t* __restrict__ y1, ushort_t* __restrict__ y2)
{
    __shared__ short sA1[2][128 * KP];
    __shared__ short sA2[2][128 * KP];
    __shared__ short sB [2][64 * KP];

    const int tid = threadIdx.x;
    const int l0 = blockIdx.x * 64;
    const int o0 = blockIdx.y * 128;
    const int b  = blockIdx.z;

    const int wv = tid >> 6;
    const int lane = tid & 63;
    const int m = lane & 15;
    const int quad = lane >> 4;

    const float* xb = x + (size_t)b * CCH * L;

    const int sl = tid & 63, soct = tid >> 6;
    const int sr = tid & 127, sh = tid >> 7;

    f32x4 acc1[2][4], acc2[2][4];
    #pragma unroll
    for (int io = 0; io < 2; ++io)
        #pragma unroll
        for (int jl = 0; jl < 4; ++jl) {
            acc1[io][jl] = (f32x4){0.f,0.f,0.f,0.f};
            acc2[io][jl] = (f32x4){0.f,0.f,0.f,0.f};
        }

    float fx[8];
    uint4 pw1a, pw1b, pw2a, pw2b;

    auto LOADT = [&](int s) {
        const int k0 = s * 32;
        const float* xs = xb + (size_t)(k0 + soct * 8) * L + l0 + sl;
        #pragma unroll
        for (int j = 0; j < 8; ++j) fx[j] = xs[(size_t)j * L];
        const uint4* wp = (const uint4*)&wb1[(size_t)(o0 + sr) * CCH + k0 + sh * 16];
        pw1a = wp[0]; pw1b = wp[1];
        const uint4* wq = (const uint4*)&wb2[(size_t)(o0 + sr) * CCH + k0 + sh * 16];
        pw2a = wq[0]; pw2b = wq[1];
    };
    auto STORET = [&](int buf) {
        uint4 v;
        v.x = pk_bf16(fx[0], fx[1]);
        v.y = pk_bf16(fx[2], fx[3]);
        v.z = pk_bf16(fx[4], fx[5]);
        v.w = pk_bf16(fx[6], fx[7]);
        *(uint4*)&sB[buf][sl * KP + soct * 8] = v;
        *(uint4*)&sA1[buf][sr * KP + sh * 16]     = pw1a;
        *(uint4*)&sA1[buf][sr * KP + sh * 16 + 8] = pw1b;
        *(uint4*)&sA2[buf][sr * KP + sh * 16]     = pw2a;
        *(uint4*)&sA2[buf][sr * KP + sh * 16 + 8] = pw2b;
    };

    LOADT(0);
    STORET(0);
    __syncthreads();

    for (int s = 0; s < 8; ++s) {
        const int buf = s & 1;
        if (s < 7) LOADT(s + 1);           // prefetch next tile (no wait yet)

        short8 a1[2], a2[2], bfr[4];
        #pragma unroll
        for (int io = 0; io < 2; ++io) {
            a1[io] = *(const short8*)&sA1[buf][(wv * 32 + io * 16 + m) * KP + quad * 8];
            a2[io] = *(const short8*)&sA2[buf][(wv * 32 + io * 16 + m) * KP + quad * 8];
        }
        #pragma unroll
        for (int jl = 0; jl < 4; ++jl)
            bfr[jl] = *(const short8*)&sB[buf][(jl * 16 + m) * KP + quad * 8];
        #pragma unroll
        for (int io = 0; io < 2; ++io)
            #pragma unroll
            for (int jl = 0; jl < 4; ++jl) {
                acc1[io][jl] = __builtin_amdgcn_mfma_f32_16x16x32_bf16(a1[io], bfr[jl], acc1[io][jl], 0, 0, 0);
                acc2[io][jl] = __builtin_amdgcn_mfma_f32_16x16x32_bf16(a2[io], bfr[jl], acc2[io][jl], 0, 0, 0);
            }

        if (s < 7) STORET(buf ^ 1);        // write next tile to other buffer
        __syncthreads();
    }

    #pragma unroll
    for (int io = 0; io < 2; ++io)
        #pragma unroll
        for (int reg = 0; reg < 4; ++reg) {
            const int o = o0 + wv * 32 + io * 16 + quad * 4 + reg;
            const float bb1 = b1[o], bb2 = b2[o];
            const size_t ro = ((size_t)b * CCH + o) * L + l0 + m;
            unsigned u1a = pk_bf16(acc1[io][0][reg] + bb1, acc1[io][1][reg] + bb1);
            unsigned u1b = pk_bf16(acc1[io][2][reg] + bb1, acc1[io][3][reg] + bb1);
            unsigned u2a = pk_bf16(acc2[io][0][reg] + bb2, acc2[io][1][reg] + bb2);
            unsigned u2b = pk_bf16(acc2[io][2][reg] + bb2, acc2[io][3][reg] + bb2);
            y1[ro]      = (ushort_t)u1a;
            y1[ro + 16] = (ushort_t)(u1a >> 16);
            y1[ro + 32] = (ushort_t)u1b;
            y1[ro + 48] = (ushort_t)(u1b >> 16);
            y2[ro]      = (ushort_t)u2a;
            y2[ro + 16] = (ushort_t)(u2a >> 16);
            y2[ro + 32] = (ushort_t)u2b;
            y2[ro + 48] = (ushort_t)(u2b >> 16);
        }
}

// ---------------------------------------------------------------------------
// Single conv1x1 via bf16 MFMA — v2: same double-buffer + prefetch pipeline.
// LDS 2x15.4 KB = 30.7 KB; __launch_bounds__(256,4).
// ---------------------------------------------------------------------------
__global__ __launch_bounds__(256, 4) void single_gemm_k(
    const ushort_t* __restrict__ x,
    const ushort_t* __restrict__ wb, const float* __restrict__ bb,
    ushort_t* __restrict__ y)
{
    __shared__ short sA[2][128 * KP];
    __shared__ short sB[2][64 * KP];

    const int tid = threadIdx.x;
    const int l0 = blockIdx.x * 64;
    const int o0 = blockIdx.y * 128;
    const int b  = blockIdx.z;

    const int wv = tid >> 6;
    const int lane = tid & 63;
    const int m = lane & 15;
    const int quad = lane >> 4;

    const ushort_t* xb = x + (size_t)b * CCH * L;

    const int sl = tid & 63, soct = tid >> 6;
    const int sr = tid & 127, sh = tid >> 7;

    f32x4 acc[2][4];
    #pragma unroll
    for (int io = 0; io < 2; ++io)
        #pragma unroll
        for (int jl = 0; jl < 4; ++jl)
            acc[io][jl] = (f32x4){0.f,0.f,0.f,0.f};

    ushort_t hx[8];
    uint4 pwa, pwb;

    auto LOADT = [&](int s) {
        const int k0 = s * 32;
        const ushort_t* xs = xb + (size_t)(k0 + soct * 8) * L + l0 + sl;
        #pragma unroll
        for (int j = 0; j < 8; ++j) hx[j] = xs[(size_t)j * L];
        const uint4* wp = (const uint4*)&wb[(size_t)(o0 + sr) * CCH + k0 + sh * 16];
        pwa = wp[0]; pwb = wp[1];
    };
    auto STORET = [&](int buf) {
        short8 v;
        #pragma unroll
        for (int j = 0; j < 8; ++j) v[j] = (short)hx[j];
        *(short8*)&sB[buf][sl * KP + soct * 8] = v;
        *(uint4*)&sA[buf][sr * KP + sh * 16]     = pwa;
        *(uint4*)&sA[buf][sr * KP + sh * 16 + 8] = pwb;
    };

    LOADT(0);
    STORET(0);
    __syncthreads();

    for (int s = 0; s < 8; ++s) {
        const int buf = s & 1;
        if (s < 7) LOADT(s + 1);

        short8 a[2], bfr[4];
        #pragma unroll
        for (int io = 0; io < 2; ++io)
            a[io] = *(const short8*)&sA[buf][(wv * 32 + io * 16 + m) * KP + quad * 8];
        #pragma unroll
        for (int jl = 0; jl < 4; ++jl)
            bfr[jl] = *(const short8*)&sB[buf][(jl * 16 + m) * KP + quad * 8];
        #pragma unroll
        for (int io = 0; io < 2; ++io)
            #pragma unroll
            for (int jl = 0; jl < 4; ++jl)
                acc[io][jl] = __builtin_amdgcn_mfma_f32_16x16x32_bf16(a[io], bfr[jl], acc[io][jl], 0, 0, 0);

        if (s < 7) STORET(buf ^ 1);
        __syncthreads();
    }

    #pragma unroll
    for (int io = 0; io < 2; ++io)
        #pragma unroll
        for (int reg = 0; reg < 4; ++reg) {
            const int o = o0 + wv * 32 + io * 16 + quad * 4 + reg;
            const float b0 = bb[o];
            const size_t ro = ((size_t)b * CCH + o) * L + l0 + m;
            unsigned ua = pk_bf16(acc[io][0][reg] + b0, acc[io][1][reg] + b0);
            unsigned ub = pk_bf16(acc[io][2][reg] + b0, acc[io][3][reg] + b0);
            y[ro]      = (ushort_t)ua;
            y[ro + 16] = (ushort_t)(ua >> 16);
            y[ro + 32] = (ushort_t)ub;
            y[ro + 48] = (ushort_t)(ub >> 16);
        }
}

// ---------------------------------------------------------------------------
// BatchNorm stats over bf16 tensor -> finalized scale/shift.
// kscale: extra factor folded into scale/shift (log2e for the K channel).
// ---------------------------------------------------------------------------
__device__ __forceinline__ void bn_stats_body(
    const ushort_t* y, const float* gamma, const float* beta,
    float* scale, float* shift, int c, int tid, float kscale)
{
    float s = 0.f, s2 = 0.f;
    for (int b = 0; b < NB; ++b) {
        const uint4* p = (const uint4*)(y + ((size_t)b * CCH + c) * L);
        #pragma unroll
        for (int r = 0; r < 2; ++r) {
            uint4 v = p[r * 256 + tid];
            unsigned w[4] = {v.x, v.y, v.z, v.w};
            #pragma unroll
            for (int u = 0; u < 4; ++u) {
                float a = bflo(w[u]), bb = bfhi(w[u]);
                s  += a + bb;
                s2 += a * a + bb * bb;
            }
        }
    }
    #pragma unroll
    for (int off = 32; off > 0; off >>= 1) {
        s  += __shfl_down(s, off);
        s2 += __shfl_down(s2, off);
    }
    __shared__ float red[2][4];
    if ((tid & 63) == 0) { red[0][tid >> 6] = s; red[1][tid >> 6] = s2; }
    __syncthreads();
    if (tid == 0) {
        float S  = red[0][0] + red[0][1] + red[0][2] + red[0][3];
        float S2 = red[1][0] + red[1][1] + red[1][2] + red[1][3];
        const float invN = 1.f / (NB * (float)L);
        float mean = S * invN;
        float var  = S2 * invN - mean * mean;
        float rstd = rsqrtf(var + 1e-5f);
        float g = gamma[c];
        scale[c] = kscale * g * rstd;
        shift[c] = kscale * (beta[c] - mean * g * rstd);
    }
}

// two tensors in one launch: blockIdx.x in [0,512). K channel gets log2e fold.
__global__ __launch_bounds__(256) void bn_stats2_k(
    const ushort_t* __restrict__ y1, const float* __restrict__ g1, const float* __restrict__ be1,
    float* __restrict__ sc1, float* __restrict__ sh1,
    const ushort_t* __restrict__ y2, const float* __restrict__ g2, const float* __restrict__ be2,
    float* __restrict__ sc2, float* __restrict__ sh2)
{
    const int c = blockIdx.x & 255;
    if (blockIdx.x < 256) bn_stats_body(y1, g1, be1, sc1, sh1, c, threadIdx.x, LOG2E);
    else                  bn_stats_body(y2, g2, be2, sc2, sh2, c, threadIdx.x, 1.0f);
}

// ---------------------------------------------------------------------------
// Attention v6 (unchanged from R3 — passing, <43 us): fused single-pass with
// race-free phased LDS read-modify-write (no LDS atomics — R1 lesson: CAS
// loop serializes 4x). Collision pairs are only dtid in {455,456}; sub-phase
// A (tid<455) and B (tid>=455) are each internally alias-free; cross-
// iteration pairs are separated by the barriers.
// LDS 41824 B -> 3 blocks/CU.
// ---------------------------------------------------------------------------
__global__ __launch_bounds__(512, 6) void attention_k(
    const float* __restrict__ x,
    const ushort_t* __restrict__ y1,
    const ushort_t* __restrict__ y2,
    const float* __restrict__ s1sc, const float* __restrict__ s1sh,
    const float* __restrict__ s2sc, const float* __restrict__ s2sh,
    ushort_t* __restrict__ pre)
{
    __shared__ unsigned sKQg[4240];   // [GOF+s] = packed bf16 (k', q); guards zero
    __shared__ ushort_t sXg [4240];   // [GOF+s] = bf16 x; guards zero
    __shared__ float    accF[L];      // output accumulator (16 KB)

    const int bc = blockIdx.x;
    const int tid = threadIdx.x;
    const int ch = bc & 255;
    const size_t off = (size_t)bc * L;

    const float sc1 = s1sc[ch], sh1 = s1sh[ch];   // pre-scaled by log2e
    const float sc2 = s2sc[ch], sh2 = s2sh[ch];

    // ---- stage + guards + zero accumulator ---------------------------
    if (tid < GOF)  { sKQg[tid] = 0; sXg[tid] = 0; }
    if (tid < 72)   { sKQg[GOF + 4096 + tid] = 0; sXg[GOF + 4096 + tid] = 0; }
    {
        float4 z = {0.f, 0.f, 0.f, 0.f};
        ((float4*)accF)[tid]       = z;
        ((float4*)accF)[tid + 512] = z;
    }
    {
        uint4 ak = ((const uint4*)(y1 + off))[tid];
        uint4 aq = ((const uint4*)(y2 + off))[tid];
        float4 xa = ((const float4*)(x + off))[2 * tid];
        float4 xb = ((const float4*)(x + off))[2 * tid + 1];
        unsigned wk[4] = {ak.x, ak.y, ak.z, ak.w};
        unsigned wq[4] = {aq.x, aq.y, aq.z, aq.w};
        unsigned kq[8];
        #pragma unroll
        for (int u = 0; u < 4; ++u) {
            float klo = fmaxf(fmaf(bflo(wk[u]), sc1, sh1), 0.f);
            float khi = fmaxf(fmaf(bfhi(wk[u]), sc1, sh1), 0.f);
            float qlo = fmaxf(fmaf(bflo(wq[u]), sc2, sh2), 0.f);
            float qhi = fmaxf(fmaf(bfhi(wq[u]), sc2, sh2), 0.f);
            kq[2*u]   = (unsigned)f2bf(klo) | ((unsigned)f2bf(qlo) << 16);
            kq[2*u+1] = (unsigned)f2bf(khi) | ((unsigned)f2bf(qhi) << 16);
        }
        *(uint4*)&sKQg[GOF + 8 * tid]     = make_uint4(kq[0], kq[1], kq[2], kq[3]);
        *(uint4*)&sKQg[GOF + 8 * tid + 4] = make_uint4(kq[4], kq[5], kq[6], kq[7]);
        float xv[8] = {xa.x, xa.y, xa.z, xa.w, xb.x, xb.y, xb.z, xb.w};
        unsigned xp[4];
        #pragma unroll
        for (int u = 0; u < 4; ++u)
            xp[u] = (unsigned)f2bf(xv[2*u]) | ((unsigned)f2bf(xv[2*u+1]) << 16);
        *(uint4*)&sXg[GOF + 8 * tid] = make_uint4(xp[0], xp[1], xp[2], xp[3]);
    }
    __syncthreads();

    // ---- fused per-window softmax + phased scatter-accumulate ---------
    {
        const int fbase = 9 * tid;
        #pragma unroll
        for (int r = 0; r < 8; ++r) {
            const int f  = fbase + 4608 * r;       // f = 9 * window_index
            const int t  = f >> 12;
            const int fl = f & 4095;
            unsigned wv[9];
            float    xw[9];
            const bool fastp = (fl < 4088);
            if (fastp) {                           // fast path: single tap t
                const int di = (t * 86) >> 8;
                const int dj = t - 3 * di;
                const int cbad = (dj == 0) ? 0 : ((dj == 2) ? 63 : 99);
                const int base = fl + (di << 6) + dj - 65 + GOF;
                #pragma unroll
                for (int j = 0; j < 9; ++j) {
                    wv[j] = sKQg[base + j];
                    xw[j] = bfu(sXg[base + j]);
                }
                #pragma unroll
                for (int j = 0; j < 9; ++j) {
                    int c = (fl + j) & 63;
                    bool bad = (c == cbad);
                    wv[j] = bad ? 0u  : wv[j];
                    xw[j] = bad ? 0.f : xw[j];
                }
            } else {                               // straddle: generic decode
                #pragma unroll
                for (int j = 0; j < 9; ++j) {
                    int fj = f + j;
                    int tj = fj >> 12, lj = fj & 4095;
                    int dij = (tj * 86) >> 8, djj = tj - 3 * dij;
                    int idx = lj + (dij << 6) + djj - 65 + GOF;
                    unsigned wr = sKQg[idx];
                    float    xr = bfu(sXg[idx]);
                    int c = lj & 63;
                    int cb = (djj == 0) ? 0 : ((djj == 2) ? 63 : 99);
                    bool bad = (c == cb);
                    wv[j] = bad ? 0u  : wr;
                    xw[j] = bad ? 0.f : xr;
                }
            }
            const unsigned cw = wv[4];
            const float kc = bflo(cw), qc = bfhi(cw);
            float e[9];
            #pragma unroll
            for (int j = 0; j < 9; ++j)
                e[j] = __builtin_amdgcn_exp2f(bflo(wv[j]) * qc + kc * bfhi(wv[j]));
            float s = (((e[0] + e[1]) + (e[2] + e[3])) +
                       ((e[4] + e[5]) + (e[6] + e[7]))) + e[8];
            const float rinv = __builtin_amdgcn_rcpf(s);
            float cj[9];
            #pragma unroll
            for (int j = 0; j < 9; ++j)
                cj[j] = e[j] * rinv * xw[j];

            // phased race-free RMW (see header comment)
            __syncthreads();
            if (tid < 455) {
                if (fastp) {
                    #pragma unroll
                    for (int j = 0; j < 9; ++j) accF[fl + j] += cj[j];
                } else {
                    #pragma unroll
                    for (int j = 0; j < 9; ++j) accF[(f + j) & 4095] += cj[j];
                }
            }
            __syncthreads();
            if (tid >= 455) {
                if (fastp) {
                    #pragma unroll
                    for (int j = 0; j < 9; ++j) accF[fl + j] += cj[j];
                } else {
                    #pragma unroll
                    for (int j = 0; j < 9; ++j) accF[(f + j) & 4095] += cj[j];
                }
            }
        }
    }
    __syncthreads();

    // ---- write out (pairs -> 4B/lane coalesced stores) ----------------
    {
        unsigned* po = (unsigned*)(pre + off);
        #pragma unroll
        for (int rr = 0; rr < 4; ++rr) {
            const int p = rr * 512 + tid;
            po[p] = pk_bf16(accF[2 * p], accF[2 * p + 1]);
        }
    }
}

// ---------------------------------------------------------------------------
// Fused final BN: per-channel stats + apply + ReLU in one kernel.
// Block c: stage channel's 4x4096 bf16 (32 KB LDS), reduce, finalize, apply.
// ---------------------------------------------------------------------------
__global__ __launch_bounds__(256) void bn_fused_k(
    const ushort_t* __restrict__ yf,
    const float* __restrict__ gf, const float* __restrict__ bef,
    float* __restrict__ out)
{
    __shared__ uint4 sY[2048];       // 4 batches x 512 uint4 = 32 KB
    __shared__ float red[2][4];
    __shared__ float fsc, fsh;

    const int c = blockIdx.x, tid = threadIdx.x;
    float s = 0.f, s2 = 0.f;
    #pragma unroll
    for (int b = 0; b < NB; ++b) {
        const uint4* p = (const uint4*)(yf + ((size_t)b * CCH + c) * L);
        #pragma unroll
        for (int r = 0; r < 2; ++r) {
            uint4 v = p[r * 256 + tid];
            sY[b * 512 + r * 256 + tid] = v;
            unsigned w[4] = {v.x, v.y, v.z, v.w};
            #pragma unroll
            for (int u = 0; u < 4; ++u) {
                float a = bflo(w[u]), bb = bfhi(w[u]);
                s  += a + bb;
                s2 += a * a + bb * bb;
            }
        }
    }
    #pragma unroll
    for (int off = 32; off > 0; off >>= 1) {
        s  += __shfl_down(s, off);
        s2 += __shfl_down(s2, off);
    }
    if ((tid & 63) == 0) { red[0][tid >> 6] = s; red[1][tid >> 6] = s2; }
    __syncthreads();
    if (tid == 0) {
        float S  = red[0][0] + red[0][1] + red[0][2] + red[0][3];
        float S2 = red[1][0] + red[1][1] + red[1][2] + red[1][3];
        const float invN = 1.f / (NB * (float)L);
        float mean = S * invN;
        float var  = S2 * invN - mean * mean;
        float rstd = rsqrtf(var + 1e-5f);
        float g = gf[c];
        fsc = g * rstd;
        fsh = bef[c] - mean * g * rstd;
    }
    __syncthreads();
    const float sc = fsc, sh = fsh;

    #pragma unroll
    for (int b = 0; b < NB; ++b) {
        float4* o = (float4*)(out + ((size_t)b * CCH + c) * L);
        #pragma unroll
        for (int r = 0; r < 2; ++r) {
            uint4 v = sY[b * 512 + r * 256 + tid];
            unsigned w[4] = {v.x, v.y, v.z, v.w};
            float4 o0, o1;
            o0.x = fmaxf(fmaf(bflo(w[0]), sc, sh), 0.f);
            o0.y = fmaxf(fmaf(bfhi(w[0]), sc, sh), 0.f);
            o0.z = fmaxf(fmaf(bflo(w[1]), sc, sh), 0.f);
            o0.w = fmaxf(fmaf(bfhi(w[1]), sc, sh), 0.f);
            o1.x = fmaxf(fmaf(bflo(w[2]), sc, sh), 0.f);
            o1.y = fmaxf(fmaf(bfhi(w[2]), sc, sh), 0.f);
            o1.z = fmaxf(fmaf(bflo(w[3]), sc, sh), 0.f);
            o1.w = fmaxf(fmaf(bfhi(w[3]), sc, sh), 0.f);
            int i = r * 256 + tid;
            o[2 * i]     = o0;
            o[2 * i + 1] = o1;
        }
    }
}

// ---------------------------------------------------------------------------
extern "C" void kernel_launch(void* const* d_in, const int* in_sizes, int n_in,
                              void* d_out, int out_size, void* d_ws, size_t ws_size,
                              hipStream_t stream) {
    const float* x   = (const float*)d_in[0];
    const float* w1  = (const float*)d_in[1];
    const float* b1  = (const float*)d_in[2];
    const float* g1  = (const float*)d_in[3];
    const float* be1 = (const float*)d_in[4];
    const float* w2  = (const float*)d_in[5];
    const float* b2  = (const float*)d_in[6];
    const float* g2  = (const float*)d_in[7];
    const float* be2 = (const float*)d_in[8];
    const float* wf  = (const float*)d_in[9];
    const float* bf  = (const float*)d_in[10];
    const float* gf  = (const float*)d_in[11];
    const float* bef = (const float*)d_in[12];
    float* out = (float*)d_out;

    const size_t NEL = (size_t)NB * CCH * L;       // 4194304
    ushort_t* y1b = (ushort_t*)d_ws;               // conv1 out (bf16); later yf
    ushort_t* y2b = y1b + NEL;                     // conv2 out (bf16); later pre
    float* st = (float*)(y2b + NEL);               // stats: 4 x 256
    float* s1sc = st,        *s1sh = st + 256;
    float* s2sc = st + 512,  *s2sh = st + 768;
    ushort_t* wb1 = (ushort_t*)(st + 1536);        // bf16 weights: 3 x 64K
    ushort_t* wb2 = wb1 + CCH * CCH;
    ushort_t* wbf = wb2 + CCH * CCH;

    wcvt_k<<<192, 256, 0, stream>>>(w1, w2, wf, wb1, wb2, wbf);
    dim3 gg(64, 2, 4);
    dual_gemm_k<<<gg, 256, 0, stream>>>(x, wb1, b1, wb2, b2, y1b, y2b);
    bn_stats2_k<<<512, 256, 0, stream>>>(y1b, g1, be1, s1sc, s1sh,
                                         y2b, g2, be2, s2sc, s2sh);
    attention_k<<<NB * CCH, 512, 0, stream>>>(x, y1b, y2b,
                                              s1sc, s1sh, s2sc, s2sh,
                                              /*pre=*/y2b);
    single_gemm_k<<<gg, 256, 0, stream>>>(/*pre=*/y2b, wbf, bf, /*yf=*/y1b);
    bn_fused_k<<<256, 256, 0, stream>>>(y1b, gf, bef, out);
}